// Round 1
// baseline (686.300 us; speedup 1.0000x reference)
//
#include <hip/hip_runtime.h>
#include <math.h>

// Problem shape (fixed by the reference): B=16, S=4096, E=2048, WIN=64.
#define EDIM 2048
#define SLEN 4096

// Stage 1: one wave (64 lanes) computes one row's dot(x[row,:], W) + b,
// applies the mask, writes score to workspace. 4 waves per 256-thread block.
__global__ __launch_bounds__(256) void score_kernel(
    const float* __restrict__ x,
    const int*   __restrict__ mask,
    const float* __restrict__ W,
    const float* __restrict__ bias,
    float* __restrict__ s_out)
{
    __shared__ float4 wsh[EDIM / 4];  // 512 float4 = 8 KB

    const int tid = threadIdx.x;

    // Stage W into LDS: 512 float4 across 256 threads (2 each), coalesced.
    const float4* W4 = (const float4*)W;
    wsh[tid]       = W4[tid];
    wsh[tid + 256] = W4[tid + 256];
    __syncthreads();

    const int wave = tid >> 6;
    const int lane = tid & 63;
    const int row  = blockIdx.x * 4 + wave;

    const float4* x4 = (const float4*)(x + (size_t)row * EDIM);

    float acc = 0.0f;
#pragma unroll
    for (int k = 0; k < 8; ++k) {
        float4 xv = x4[lane + 64 * k];   // coalesced: lane i -> consecutive 16B
        float4 wv = wsh[lane + 64 * k];
        acc = fmaf(xv.x, wv.x, acc);
        acc = fmaf(xv.y, wv.y, acc);
        acc = fmaf(xv.z, wv.z, acc);
        acc = fmaf(xv.w, wv.w, acc);
    }

    // Wave-level reduction across all 64 lanes.
#pragma unroll
    for (int off = 32; off > 0; off >>= 1)
        acc += __shfl_down(acc, off, 64);

    if (lane == 0) {
        float v = mask[row] ? (acc + bias[0]) : 0.0f;
        s_out[row] = v;
    }
}

// Stage 2: one block per batch. Scores in LDS; each thread computes direct
// window sums for strided positions, tracks local max; block max-reduce.
// max(window_mean) == max(window_sum)/win since win > 0.
__global__ __launch_bounds__(256) void window_max_kernel(
    const float* __restrict__ s,
    const int*   __restrict__ win_ptr,
    float* __restrict__ out)
{
    __shared__ float sh[SLEN];      // 16 KB
    __shared__ float red[256];

    const int b   = blockIdx.x;
    const int tid = threadIdx.x;
    const float* sb = s + (size_t)b * SLEN;

    for (int i = tid; i < SLEN; i += 256)
        sh[i] = sb[i];
    __syncthreads();

    const int win  = *win_ptr;
    const int npos = SLEN - win + 1;

    float best = -INFINITY;
    for (int p = tid; p < npos; p += 256) {
        float sum = 0.0f;
        for (int j = 0; j < win; ++j)
            sum += sh[p + j];
        best = fmaxf(best, sum);
    }

    red[tid] = best;
    __syncthreads();
    for (int k = 128; k > 0; k >>= 1) {
        if (tid < k) red[tid] = fmaxf(red[tid], red[tid + k]);
        __syncthreads();
    }
    if (tid == 0)
        out[b] = red[0] / (float)win;
}

extern "C" void kernel_launch(void* const* d_in, const int* in_sizes, int n_in,
                              void* d_out, int out_size, void* d_ws, size_t ws_size,
                              hipStream_t stream) {
    const float* x    = (const float*)d_in[0];  // [B,S,E] f32
    const int*   mask = (const int*)  d_in[1];  // [B,S]   bool->int
    const float* W    = (const float*)d_in[2];  // [E]     f32
    const float* bias = (const float*)d_in[3];  // [1]     f32
    const int*   win  = (const int*)  d_in[4];  // scalar  int

    float* out = (float*)d_out;                 // [B] f32
    float* s   = (float*)d_ws;                  // [B*S] f32 scratch (256 KB)

    const int rows = in_sizes[1];               // B*S = 65536
    const int B    = out_size;                  // 16

    score_kernel<<<rows / 4, 256, 0, stream>>>(x, mask, W, bias, s);
    window_max_kernel<<<B, 256, 0, stream>>>(s, win, out);
}